// Round 1
// baseline (132.248 us; speedup 1.0000x reference)
//
#include <hip/hip_runtime.h>

#define SEQ 2048
#define DIM 6
#define BLOCK 256

// K rows stored as [S][8]: {k0..k5 scaled by log2(e), bias2 (0 or -1.44e6), 0}
// V rows stored as [S][8]: {v0..v5, 1.0 (denominator counter), 0}

__launch_bounds__(BLOCK)
__global__ void attn_kernel(const float* __restrict__ X,
                            const int* __restrict__ mask,
                            const float* __restrict__ Wq, const float* __restrict__ bq,
                            const float* __restrict__ Wk, const float* __restrict__ bk,
                            const float* __restrict__ Wv, const float* __restrict__ bv,
                            float* __restrict__ out) {
    extern __shared__ float smem[];
    float* Ksm = smem;            // [SEQ][8]
    float* Vsm = smem + SEQ * 8;  // [SEQ][8]

    const int b = blockIdx.y;
    const int tid = threadIdx.x;
    const float* Xb = X + (size_t)b * SEQ * DIM;
    const int* mb = mask + (size_t)b * SEQ;

    const float L2E = 1.44269504088896f;

    // ---- Stage K', V' for the whole batch into LDS ----
    for (int t = tid; t < SEQ; t += BLOCK) {
        // X row: byte offset t*24, 8-byte aligned -> float2 loads
        const float2* xp = reinterpret_cast<const float2*>(Xb + t * DIM);
        float2 x01 = xp[0], x23 = xp[1], x45 = xp[2];
        float x[DIM] = {x01.x, x01.y, x23.x, x23.y, x45.x, x45.y};
#pragma unroll
        for (int i = 0; i < DIM; ++i) {
            float kk = bk[i];
            float vv = bv[i];
#pragma unroll
            for (int j = 0; j < DIM; ++j) {
                kk = fmaf(Wk[i * DIM + j], x[j], kk);
                vv = fmaf(Wv[i * DIM + j], x[j], vv);
            }
            Ksm[t * 8 + i] = kk * L2E;
            Vsm[t * 8 + i] = vv;
        }
        Ksm[t * 8 + 6] = (mb[t] == 0) ? -1.44269504e6f : 0.0f;
        Ksm[t * 8 + 7] = 0.0f;
        Vsm[t * 8 + 6] = 1.0f;
        Vsm[t * 8 + 7] = 0.0f;
    }
    __syncthreads();

    // ---- Each thread owns one query row ----
    const int s = blockIdx.x * BLOCK + tid;
    float q[8];
    {
        const float2* xp = reinterpret_cast<const float2*>(Xb + s * DIM);
        float2 x01 = xp[0], x23 = xp[1], x45 = xp[2];
        float x[DIM] = {x01.x, x01.y, x23.x, x23.y, x45.x, x45.y};
        const bool rm = (mb[s] == 0);  // masked row -> uniform softmax over ALL t
#pragma unroll
        for (int i = 0; i < DIM; ++i) {
            float qq = bq[i];
#pragma unroll
            for (int j = 0; j < DIM; ++j) qq = fmaf(Wq[i * DIM + j], x[j], qq);
            q[i] = rm ? 0.0f : qq;
        }
        q[6] = rm ? 0.0f : 1.0f;  // bias multiplier
        q[7] = 0.0f;
    }

    float acc0 = 0.f, acc1 = 0.f, acc2 = 0.f, acc3 = 0.f,
          acc4 = 0.f, acc5 = 0.f, acc6 = 0.f;  // acc6 = softmax denom

#pragma unroll 8
    for (int t = 0; t < SEQ; ++t) {
        const float4 ka = *reinterpret_cast<const float4*>(&Ksm[t * 8]);
        const float4 kb2 = *reinterpret_cast<const float4*>(&Ksm[t * 8 + 4]);
        float arg = q[0] * ka.x;
        arg = fmaf(q[1], ka.y, arg);
        arg = fmaf(q[2], ka.z, arg);
        arg = fmaf(q[3], ka.w, arg);
        arg = fmaf(q[4], kb2.x, arg);
        arg = fmaf(q[5], kb2.y, arg);
        arg = fmaf(q[6], kb2.z, arg);  // + bias2_t * bmul
        const float p = __builtin_amdgcn_exp2f(arg);
        const float4 va = *reinterpret_cast<const float4*>(&Vsm[t * 8]);
        const float4 vb = *reinterpret_cast<const float4*>(&Vsm[t * 8 + 4]);
        acc0 = fmaf(p, va.x, acc0);
        acc1 = fmaf(p, va.y, acc1);
        acc2 = fmaf(p, va.z, acc2);
        acc3 = fmaf(p, va.w, acc3);
        acc4 = fmaf(p, vb.x, acc4);
        acc5 = fmaf(p, vb.y, acc5);
        acc6 = fmaf(p, vb.z, acc6);  // denom += p * 1.0
    }

    const float inv = __builtin_amdgcn_rcpf(acc6);
    float* o = out + ((size_t)b * SEQ + s) * DIM;
    o[0] = acc0 * inv;
    o[1] = acc1 * inv;
    o[2] = acc2 * inv;
    o[3] = acc3 * inv;
    o[4] = acc4 * inv;
    o[5] = acc5 * inv;
}

extern "C" void kernel_launch(void* const* d_in, const int* in_sizes, int n_in,
                              void* d_out, int out_size, void* d_ws, size_t ws_size,
                              hipStream_t stream) {
    const float* X  = (const float*)d_in[0];
    const int* mask = (const int*)d_in[1];
    const float* Wq = (const float*)d_in[2];
    const float* bq = (const float*)d_in[3];
    const float* Wk = (const float*)d_in[4];
    const float* bk = (const float*)d_in[5];
    const float* Wv = (const float*)d_in[6];
    const float* bv = (const float*)d_in[7];
    float* out = (float*)d_out;

    const int B = in_sizes[0] / (SEQ * DIM);

    const size_t shmem = (size_t)SEQ * 8 * sizeof(float) * 2;  // 128 KiB
    hipFuncSetAttribute(reinterpret_cast<const void*>(attn_kernel),
                        hipFuncAttributeMaxDynamicSharedMemorySize, (int)shmem);

    dim3 grid(SEQ / BLOCK, B);
    attn_kernel<<<grid, BLOCK, shmem, stream>>>(X, mask, Wq, bq, Wk, bk, Wv, bv, out);
}

// Round 2
// 77.518 us; speedup vs baseline: 1.7060x; 1.7060x over previous
//
#include <hip/hip_runtime.h>

#define SEQ 2048
#define DIM 6
#define BLOCK 256
#define RROWS 4  // query rows per thread

typedef _Float16 half8 __attribute__((ext_vector_type(8)));

// K' row (fp16 x8): {k0..k5 scaled by log2(e), bias (0 or -1024), 0}
// V' row (fp16 x8): {v0..v5, 0, 0}   (denominator handled as acc += p)
// partials layout: [B][T][SEQ][8] f32: {num0..num5, denom, pad}

__launch_bounds__(BLOCK)
__global__ void attn_partial(const float* __restrict__ X,
                             const int* __restrict__ mask,
                             const float* __restrict__ Wq, const float* __restrict__ bq,
                             const float* __restrict__ Wk, const float* __restrict__ bk,
                             const float* __restrict__ Wv, const float* __restrict__ bv,
                             float* __restrict__ partials,
                             int T, int chunk) {
    extern __shared__ _Float16 smem[];
    _Float16* Ksm = smem;              // [chunk][8]
    _Float16* Vsm = smem + chunk * 8;  // [chunk][8]

    const int rc = blockIdx.x;   // row chunk (0..1)
    const int tc = blockIdx.y;   // t chunk (0..T-1)
    const int b  = blockIdx.z;   // batch
    const int tid = threadIdx.x;

    const float* Xb = X + (size_t)b * SEQ * DIM;
    const int* mb = mask + (size_t)b * SEQ;
    const float L2E = 1.44269504088896f;

    // ---- Stage this t-chunk's K', V' into LDS (fp16) ----
    for (int t = tid; t < chunk; t += BLOCK) {
        const int tg = tc * chunk + t;
        const float2* xp = reinterpret_cast<const float2*>(Xb + tg * DIM);
        float2 x01 = xp[0], x23 = xp[1], x45 = xp[2];
        float x[DIM] = {x01.x, x01.y, x23.x, x23.y, x45.x, x45.y};
        half8 ks, vs;
#pragma unroll
        for (int i = 0; i < DIM; ++i) {
            float kk = bk[i];
            float vv = bv[i];
#pragma unroll
            for (int j = 0; j < DIM; ++j) {
                kk = fmaf(Wk[i * DIM + j], x[j], kk);
                vv = fmaf(Wv[i * DIM + j], x[j], vv);
            }
            ks[i] = (_Float16)(kk * L2E);
            vs[i] = (_Float16)vv;
        }
        ks[6] = (mb[tg] == 0) ? (_Float16)(-1024.0f) : (_Float16)0.0f;
        ks[7] = (_Float16)0.0f;
        vs[6] = (_Float16)0.0f;
        vs[7] = (_Float16)0.0f;
        *reinterpret_cast<half8*>(&Ksm[t * 8]) = ks;
        *reinterpret_cast<half8*>(&Vsm[t * 8]) = vs;
    }
    __syncthreads();

    // ---- Project q for RROWS rows owned by this thread ----
    float q[RROWS][7];
    int rows[RROWS];
#pragma unroll
    for (int k = 0; k < RROWS; ++k) {
        const int s = rc * (BLOCK * RROWS) + k * BLOCK + tid;
        rows[k] = s;
        const float2* xp = reinterpret_cast<const float2*>(Xb + s * DIM);
        float2 x01 = xp[0], x23 = xp[1], x45 = xp[2];
        float x[DIM] = {x01.x, x01.y, x23.x, x23.y, x45.x, x45.y};
        const bool rm = (mb[s] == 0);  // masked row -> uniform over all t
#pragma unroll
        for (int i = 0; i < DIM; ++i) {
            float qq = bq[i];
#pragma unroll
            for (int j = 0; j < DIM; ++j) qq = fmaf(Wq[i * DIM + j], x[j], qq);
            q[k][i] = rm ? 0.0f : qq;
        }
        q[k][6] = rm ? 0.0f : 1.0f;  // bias multiplier
    }

    float acc[RROWS][7];
#pragma unroll
    for (int k = 0; k < RROWS; ++k)
#pragma unroll
        for (int i = 0; i < 7; ++i) acc[k][i] = 0.0f;

    // ---- Stream the t-chunk ----
#pragma unroll 8
    for (int j = 0; j < chunk; ++j) {
        half8 kv = *reinterpret_cast<const half8*>(&Ksm[j * 8]);
        half8 vv = *reinterpret_cast<const half8*>(&Vsm[j * 8]);
        float k0 = (float)kv[0], k1 = (float)kv[1], k2 = (float)kv[2],
              k3 = (float)kv[3], k4 = (float)kv[4], k5 = (float)kv[5],
              k6 = (float)kv[6];
        float v0 = (float)vv[0], v1 = (float)vv[1], v2 = (float)vv[2],
              v3 = (float)vv[3], v4 = (float)vv[4], v5 = (float)vv[5];
        float p[RROWS];
#pragma unroll
        for (int k = 0; k < RROWS; ++k) {
            float arg = q[k][0] * k0;
            arg = fmaf(q[k][1], k1, arg);
            arg = fmaf(q[k][2], k2, arg);
            arg = fmaf(q[k][3], k3, arg);
            arg = fmaf(q[k][4], k4, arg);
            arg = fmaf(q[k][5], k5, arg);
            arg = fmaf(q[k][6], k6, arg);
            p[k] = __builtin_amdgcn_exp2f(arg);
        }
#pragma unroll
        for (int k = 0; k < RROWS; ++k) {
            acc[k][0] = fmaf(p[k], v0, acc[k][0]);
            acc[k][1] = fmaf(p[k], v1, acc[k][1]);
            acc[k][2] = fmaf(p[k], v2, acc[k][2]);
            acc[k][3] = fmaf(p[k], v3, acc[k][3]);
            acc[k][4] = fmaf(p[k], v4, acc[k][4]);
            acc[k][5] = fmaf(p[k], v5, acc[k][5]);
            acc[k][6] += p[k];
        }
    }

    // ---- Write partials ----
#pragma unroll
    for (int k = 0; k < RROWS; ++k) {
        float* pp = partials + ((((size_t)b * gridDim.y + tc) * SEQ) + rows[k]) * 8;
        float4 a0 = make_float4(acc[k][0], acc[k][1], acc[k][2], acc[k][3]);
        float4 a1 = make_float4(acc[k][4], acc[k][5], acc[k][6], 0.0f);
        *reinterpret_cast<float4*>(pp) = a0;
        *reinterpret_cast<float4*>(pp + 4) = a1;
    }
}

__launch_bounds__(BLOCK)
__global__ void attn_reduce(const float* __restrict__ partials,
                            float* __restrict__ out, int T) {
    const int idx = blockIdx.x * BLOCK + threadIdx.x;  // (b, s) flattened
    const int b = idx >> 11;
    const int s = idx & (SEQ - 1);
    float acc[8] = {0, 0, 0, 0, 0, 0, 0, 0};
    for (int tc = 0; tc < T; ++tc) {
        const float4* pp = reinterpret_cast<const float4*>(
            partials + ((((size_t)b * T + tc) * SEQ) + s) * 8);
        float4 a0 = pp[0], a1 = pp[1];
        acc[0] += a0.x; acc[1] += a0.y; acc[2] += a0.z; acc[3] += a0.w;
        acc[4] += a1.x; acc[5] += a1.y; acc[6] += a1.z;
    }
    const float inv = 1.0f / acc[6];
    float* o = out + (size_t)idx * DIM;
    float2* o2 = reinterpret_cast<float2*>(o);
    o2[0] = make_float2(acc[0] * inv, acc[1] * inv);
    o2[1] = make_float2(acc[2] * inv, acc[3] * inv);
    o2[2] = make_float2(acc[4] * inv, acc[5] * inv);
}

extern "C" void kernel_launch(void* const* d_in, const int* in_sizes, int n_in,
                              void* d_out, int out_size, void* d_ws, size_t ws_size,
                              hipStream_t stream) {
    const float* X  = (const float*)d_in[0];
    const int* mask = (const int*)d_in[1];
    const float* Wq = (const float*)d_in[2];
    const float* bq = (const float*)d_in[3];
    const float* Wk = (const float*)d_in[4];
    const float* bk = (const float*)d_in[5];
    const float* Wv = (const float*)d_in[6];
    const float* bv = (const float*)d_in[7];
    float* out = (float*)d_out;
    float* partials = (float*)d_ws;

    const int B = in_sizes[0] / (SEQ * DIM);

    // Largest T (t-chunks) whose partial buffer fits in the workspace.
    int T = 8;
    while (T > 1 && (size_t)B * T * SEQ * 8 * sizeof(float) > ws_size) T >>= 1;
    const int chunk = SEQ / T;

    const size_t shmem = (size_t)chunk * 8 * sizeof(_Float16) * 2;
    hipFuncSetAttribute(reinterpret_cast<const void*>(attn_partial),
                        hipFuncAttributeMaxDynamicSharedMemorySize, (int)shmem);

    dim3 grid1(SEQ / (BLOCK * RROWS), T, B);
    attn_partial<<<grid1, BLOCK, shmem, stream>>>(X, mask, Wq, bq, Wk, bk, Wv, bv,
                                                  partials, T, chunk);

    dim3 grid2((B * SEQ) / BLOCK);
    attn_reduce<<<grid2, BLOCK, 0, stream>>>(partials, out, T);
}

// Round 5
// 67.443 us; speedup vs baseline: 1.9609x; 1.1494x over previous
//
#include <hip/hip_runtime.h>

#define SEQ 2048
#define DIM 6
#define BLOCK 256
#define RROWS 4  // query rows per thread

typedef __fp16 half8 __attribute__((ext_vector_type(8)));
typedef __fp16 half2v __attribute__((ext_vector_type(2)));
typedef float f32x2 __attribute__((ext_vector_type(2)));

union H8 {
    half8 v8;
    half2v h2[4];
};

__device__ __forceinline__ float fdot2_(half2v a, half2v b, float c) {
#if __has_builtin(__builtin_amdgcn_fdot2)
    return __builtin_amdgcn_fdot2(a, b, c, false);
#else
    return fmaf((float)a[0], (float)b[0], fmaf((float)a[1], (float)b[1], c));
#endif
}

// K' row [chunk][8] fp16: {k0..k5 (scaled by log2 e), bias (0 or -1024), 0}
// Vp    [chunk/2][16] fp16: dim d -> (v_t[d], v_{t+1}[d]); slots 6,7 unused
// partials [B][T][SEQ][8] f32: {num0..num5, denom, pad}

__launch_bounds__(BLOCK, 4)
__global__ void attn_partial(const float* __restrict__ X,
                             const int* __restrict__ mask,
                             const float* __restrict__ Wq, const float* __restrict__ bq,
                             const float* __restrict__ Wk, const float* __restrict__ bk,
                             const float* __restrict__ Wv, const float* __restrict__ bv,
                             float* __restrict__ partials,
                             int T, int chunk) {
    extern __shared__ __fp16 smem[];
    __fp16* Ksm = smem;               // [chunk][8] fp16
    __fp16* Vpsm = smem + chunk * 8;  // [chunk/2][16] fp16 (8 half2)

    const int rc = blockIdx.x;
    const int tc = blockIdx.y;
    const int b  = blockIdx.z;
    const int tid = threadIdx.x;

    const float* Xb = X + (size_t)b * SEQ * DIM;
    const int* mb = mask + (size_t)b * SEQ;
    const float L2E = 1.44269504088896f;

    // ---- Stage K' (fp16) and pair-interleaved V' into LDS ----
    for (int j = tid; j < (chunk >> 1); j += BLOCK) {
        float vrow[2][DIM];
#pragma unroll
        for (int h = 0; h < 2; ++h) {
            const int tg = tc * chunk + 2 * j + h;
            const float2* xp = reinterpret_cast<const float2*>(Xb + tg * DIM);
            float2 x01 = xp[0], x23 = xp[1], x45 = xp[2];
            float x[DIM] = {x01.x, x01.y, x23.x, x23.y, x45.x, x45.y};
            H8 ks;
#pragma unroll
            for (int i = 0; i < DIM; ++i) {
                float kk = bk[i];
                float vv = bv[i];
#pragma unroll
                for (int jj = 0; jj < DIM; ++jj) {
                    kk = fmaf(Wk[i * DIM + jj], x[jj], kk);
                    vv = fmaf(Wv[i * DIM + jj], x[jj], vv);
                }
                ks.v8[i] = (__fp16)(kk * L2E);
                vrow[h][i] = vv;
            }
            ks.v8[6] = (mb[tg] == 0) ? (__fp16)(-1024.0f) : (__fp16)0.0f;
            ks.v8[7] = (__fp16)0.0f;
            *reinterpret_cast<half8*>(&Ksm[(2 * j + h) * 8]) = ks.v8;
        }
        H8 vp0, vp1;
#pragma unroll
        for (int i = 0; i < 4; ++i)
            vp0.h2[i] = __builtin_amdgcn_cvt_pkrtz(vrow[0][i], vrow[1][i]);
        vp1.h2[0] = __builtin_amdgcn_cvt_pkrtz(vrow[0][4], vrow[1][4]);
        vp1.h2[1] = __builtin_amdgcn_cvt_pkrtz(vrow[0][5], vrow[1][5]);
        vp1.h2[2] = __builtin_amdgcn_cvt_pkrtz(0.0f, 0.0f);
        vp1.h2[3] = __builtin_amdgcn_cvt_pkrtz(0.0f, 0.0f);
        *reinterpret_cast<half8*>(&Vpsm[j * 16]) = vp0.v8;
        *reinterpret_cast<half8*>(&Vpsm[j * 16 + 8]) = vp1.v8;
    }
    __syncthreads();

    // ---- Project q (fp16 pairs) for RROWS rows owned by this thread ----
    half2v qh[RROWS][4];
    int rows[RROWS];
#pragma unroll
    for (int k = 0; k < RROWS; ++k) {
        const int s = rc * (BLOCK * RROWS) + k * BLOCK + tid;
        rows[k] = s;
        const float2* xp = reinterpret_cast<const float2*>(Xb + s * DIM);
        float2 x01 = xp[0], x23 = xp[1], x45 = xp[2];
        float x[DIM] = {x01.x, x01.y, x23.x, x23.y, x45.x, x45.y};
        const bool rm = (mb[s] == 0);  // masked row -> p=1 over all t
        float qq[DIM];
#pragma unroll
        for (int i = 0; i < DIM; ++i) {
            float t = bq[i];
#pragma unroll
            for (int j = 0; j < DIM; ++j) t = fmaf(Wq[i * DIM + j], x[j], t);
            qq[i] = rm ? 0.0f : t;
        }
        qh[k][0] = __builtin_amdgcn_cvt_pkrtz(qq[0], qq[1]);
        qh[k][1] = __builtin_amdgcn_cvt_pkrtz(qq[2], qq[3]);
        qh[k][2] = __builtin_amdgcn_cvt_pkrtz(qq[4], qq[5]);
        qh[k][3] = __builtin_amdgcn_cvt_pkrtz(rm ? 0.0f : 1.0f, 0.0f);  // bias mult
    }

    // Packed accumulators: acc2[k][d] = (num_d from even t, num_d from odd t);
    // acc2[k][6] = packed denominator.
    f32x2 acc2[RROWS][7];
#pragma unroll
    for (int k = 0; k < RROWS; ++k)
#pragma unroll
        for (int i = 0; i < 7; ++i) acc2[k][i] = (f32x2){0.0f, 0.0f};

    // ---- Stream step pairs ----
    const int npair = chunk >> 1;
#pragma unroll 2
    for (int j = 0; j < npair; ++j) {
        H8 k0, k1, vp0, vp1;
        k0.v8 = *reinterpret_cast<const half8*>(&Ksm[(2 * j) * 8]);
        k1.v8 = *reinterpret_cast<const half8*>(&Ksm[(2 * j + 1) * 8]);
        vp0.v8 = *reinterpret_cast<const half8*>(&Vpsm[j * 16]);
        vp1.v8 = *reinterpret_cast<const half8*>(&Vpsm[j * 16 + 8]);
        // Convert V pairs to f32 once, shared across RROWS rows.
        f32x2 v01[DIM];
#pragma unroll
        for (int d = 0; d < 4; ++d)
            v01[d] = (f32x2){(float)vp0.h2[d][0], (float)vp0.h2[d][1]};
        v01[4] = (f32x2){(float)vp1.h2[0][0], (float)vp1.h2[0][1]};
        v01[5] = (f32x2){(float)vp1.h2[1][0], (float)vp1.h2[1][1]};
#pragma unroll
        for (int k = 0; k < RROWS; ++k) {
            float a0 = fdot2_(qh[k][0], k0.h2[0], 0.0f);
            a0 = fdot2_(qh[k][1], k0.h2[1], a0);
            a0 = fdot2_(qh[k][2], k0.h2[2], a0);
            a0 = fdot2_(qh[k][3], k0.h2[3], a0);
            float a1 = fdot2_(qh[k][0], k1.h2[0], 0.0f);
            a1 = fdot2_(qh[k][1], k1.h2[1], a1);
            a1 = fdot2_(qh[k][2], k1.h2[2], a1);
            a1 = fdot2_(qh[k][3], k1.h2[3], a1);
            const f32x2 p01 = {__builtin_amdgcn_exp2f(a0),
                               __builtin_amdgcn_exp2f(a1)};
#pragma unroll
            for (int d = 0; d < DIM; ++d)
                acc2[k][d] = p01 * v01[d] + acc2[k][d];  // v_pk_fma_f32
            acc2[k][6] = acc2[k][6] + p01;               // denom
        }
    }

    // ---- Write partials (horizontal add of packed accumulators) ----
#pragma unroll
    for (int k = 0; k < RROWS; ++k) {
        float* pp = partials + ((((size_t)b * T + tc) * SEQ) + rows[k]) * 8;
        *reinterpret_cast<float4*>(pp) =
            make_float4(acc2[k][0][0] + acc2[k][0][1],
                        acc2[k][1][0] + acc2[k][1][1],
                        acc2[k][2][0] + acc2[k][2][1],
                        acc2[k][3][0] + acc2[k][3][1]);
        *reinterpret_cast<float4*>(pp + 4) =
            make_float4(acc2[k][4][0] + acc2[k][4][1],
                        acc2[k][5][0] + acc2[k][5][1],
                        acc2[k][6][0] + acc2[k][6][1], 0.0f);
    }
}

__launch_bounds__(BLOCK)
__global__ void attn_reduce(const float* __restrict__ partials,
                            float* __restrict__ out, int T) {
    const int idx = blockIdx.x * BLOCK + threadIdx.x;  // (b, s) flattened
    const int b = idx >> 11;
    const int s = idx & (SEQ - 1);
    float acc[7] = {0, 0, 0, 0, 0, 0, 0};
    for (int tc = 0; tc < T; ++tc) {
        const float4* pp = reinterpret_cast<const float4*>(
            partials + ((((size_t)b * T + tc) * SEQ) + s) * 8);
        float4 a0 = pp[0], a1 = pp[1];
        acc[0] += a0.x; acc[1] += a0.y; acc[2] += a0.z; acc[3] += a0.w;
        acc[4] += a1.x; acc[5] += a1.y; acc[6] += a1.z;
    }
    const float inv = 1.0f / acc[6];
    float* o = out + (size_t)idx * DIM;
    float2* o2 = reinterpret_cast<float2*>(o);
    o2[0] = make_float2(acc[0] * inv, acc[1] * inv);
    o2[1] = make_float2(acc[2] * inv, acc[3] * inv);
    o2[2] = make_float2(acc[4] * inv, acc[5] * inv);
}

extern "C" void kernel_launch(void* const* d_in, const int* in_sizes, int n_in,
                              void* d_out, int out_size, void* d_ws, size_t ws_size,
                              hipStream_t stream) {
    const float* X  = (const float*)d_in[0];
    const int* mask = (const int*)d_in[1];
    const float* Wq = (const float*)d_in[2];
    const float* bq = (const float*)d_in[3];
    const float* Wk = (const float*)d_in[4];
    const float* bk = (const float*)d_in[5];
    const float* Wv = (const float*)d_in[6];
    const float* bv = (const float*)d_in[7];
    float* out = (float*)d_out;
    float* partials = (float*)d_ws;

    const int B = in_sizes[0] / (SEQ * DIM);

    // Largest T (t-chunks) whose partial buffer fits in the workspace.
    int T = 16;
    while (T > 1 && (size_t)B * T * SEQ * 8 * sizeof(float) > ws_size) T >>= 1;
    const int chunk = SEQ / T;

    const size_t shmem = (size_t)chunk * 8 * sizeof(__fp16) * 2;  // K + Vp

    dim3 grid1(SEQ / (BLOCK * RROWS), T, B);
    attn_partial<<<grid1, BLOCK, shmem, stream>>>(X, mask, Wq, bq, Wk, bk, Wv, bv,
                                                  partials, T, chunk);

    dim3 grid2((B * SEQ) / BLOCK);
    attn_reduce<<<grid2, BLOCK, 0, stream>>>(partials, out, T);
}